// Round 6
// baseline (261.163 us; speedup 1.0000x reference)
//
#include <hip/hip_runtime.h>
#include <hip/hip_bf16.h>

#define H_ 128
#define W_ 128
#define B_ 8
#define CIN_ 64
#define COUT_ 64

typedef __attribute__((ext_vector_type(8))) short bf16x8;
typedef __attribute__((ext_vector_type(4))) float f32x4;
typedef __attribute__((ext_vector_type(4))) unsigned int u32x4;

static __device__ __forceinline__ unsigned short f2bf(float f) {
  union { float f; unsigned int u; } a; a.f = f;
  unsigned int u = a.u;
  return (unsigned short)((u + 0x7fffu + ((u >> 16) & 1u)) >> 16);  // RNE, finite
}

static __device__ __forceinline__ unsigned int cvt_pk_bf16(float lo, float hi) {
  unsigned int r;
  asm("v_cvt_pk_bf16_f32 %0, %1, %2" : "=v"(r) : "v"(lo), "v"(hi));
  return r;
}

// ---------------- prep: transpose both weight tensors to bf16 ----------------
// dwt: (o,c,k) f32 -> [k][o(64)][c(64)] bf16      (36864 elems)
// owt: (18,c,t) f32 -> [t][om(32, zero-pad)][c(64)] bf16  (18432 elems)
__global__ __launch_bounds__(256) void prep_w(const float* __restrict__ dw,
    const float* __restrict__ ow, unsigned short* __restrict__ dwt,
    unsigned short* __restrict__ owt) {
  int id = blockIdx.x * 256 + threadIdx.x;
  if (id < 36864) {
    int c = id & 63, o = (id >> 6) & 63, k = id >> 12;
    dwt[id] = f2bf(dw[(o * 64 + c) * 9 + k]);
  } else if (id < 36864 + 18432) {
    int j = id - 36864;
    int c = j & 63, om = (j >> 6) & 31, t = j >> 11;
    owt[j] = f2bf(om < 18 ? ow[(om * 64 + c) * 9 + t] : 0.f);
  }
}

// ---------------- fused deformable block ----------------
// grid = B*16*16 (8x8 pixel tiles), block 512 = 8 waves.
// Wave wv: pixel group pg=wv&3 (16 pixels), channel-half hf=wv>>2 (K=32).
// Wave computes partial acc over its K-half; wave pairs (wv, wv+4) sum via LDS.
// x-tile in LDS: rows [ty-3,ty+11] (15) x cols [tx-4,tx+11] (16), [pt][c] bf16,
// 16B-slot XOR swizzle (c8 ^ (pt&7)). Branch-free tap loop; cold OOB repair.

__global__ __launch_bounds__(512, 6) void deform_main(const float* __restrict__ x,
    const unsigned short* __restrict__ owt, const float* __restrict__ ob,
    const unsigned short* __restrict__ dwt, const float* __restrict__ db,
    float* __restrict__ out) {
  __shared__ __attribute__((aligned(16))) unsigned short ldsx[240 * 64]; // 30 KB

  const int tid = threadIdx.x;
  // XCD swizzle: XCD x gets contiguous range = batch image b=x (L2 locality).
  const int blk = ((blockIdx.x & 7) << 8) | (blockIdx.x >> 3);
  const int b = blk >> 8;
  const int ty = ((blk >> 4) & 15) << 3;
  const int tx = (blk & 15) << 3;
  const int oy = ty - 3, ox = tx - 4;
  const int lane = tid & 63;
  const int wv = tid >> 6;          // 0..7
  const int pg = wv & 3;            // pixel group
  const int wvh = wv >> 2;          // channel half (hf)
  const int pl = lane & 15;
  const int kgrp = lane >> 4;       // 0..3
  const int pwl = (pg << 4) | pl;   // this lane's pixel 0..63
  const int pyy = ty + (pwl >> 3), pxx = tx + (pwl & 7);
  const int mc8 = (wvh << 2) | kgrp;   // tap-loop channel group (8 ch)

  // ---- phase 0: stage x tile; unit = (c8, pt), 2048 padded units, 4/thread ----
#pragma unroll
  for (int i = 0; i < 4; ++i) {
    int u = (i << 9) + tid;
    int pt = u & 255, sc8 = u >> 8;
    if (pt < 240) {
      int gy = oy + (pt >> 4), gx = ox + (pt & 15);
      bool ok = ((unsigned)gy < (unsigned)H_) && ((unsigned)gx < (unsigned)W_);
      int base = ((b * CIN_ + (sc8 << 3)) * H_ + gy) * W_ + gx;
      float v[8];
#pragma unroll
      for (int ci = 0; ci < 8; ++ci)
        v[ci] = ok ? x[base + ci * (H_ * W_)] : 0.f;
      u32x4 sv;
#pragma unroll
      for (int j = 0; j < 4; ++j) sv[j] = cvt_pk_bf16(v[2 * j], v[2 * j + 1]);
      *(u32x4*)&ldsx[(pt << 6) | ((sc8 ^ (pt & 7)) << 3)] = sv;
    }
  }
  __syncthreads();

  // ---- phase 1: offset conv via MFMA (full K; redundant across wave pairs) ----
  float ow0, ow1, ow2, ow3, owA, owB;
  {
    f32x4 aoff0 = (f32x4){0.f, 0.f, 0.f, 0.f};
    f32x4 aoff1 = (f32x4){0.f, 0.f, 0.f, 0.f};
#pragma unroll
    for (int t = 0; t < 9; ++t) {
      const int ly1 = (pwl >> 3) + (t / 3) - 1 + 3;   // [2,11]
      const int lx1 = (pwl & 7) + (t % 3) - 1 + 4;    // [3,12]
      const int ptt = (ly1 << 4) | lx1;
#pragma unroll
      for (int hf = 0; hf < 2; ++hf) {
        const int c8 = (hf << 2) | kgrp;
        union { u32x4 w; bf16x8 v; } bu;
        bu.w = *(const u32x4*)&ldsx[(ptt << 6) | ((c8 ^ (ptt & 7)) << 3)];
        bf16x8 a0 = *(const bf16x8*)&owt[(((t << 5) | pl) << 6) | (c8 << 3)];
        bf16x8 a1 = *(const bf16x8*)&owt[(((t << 5) | 16 | pl) << 6) | (c8 << 3)];
        aoff0 = __builtin_amdgcn_mfma_f32_16x16x32_bf16(a0, bu.v, aoff0, 0, 0, 0);
        aoff1 = __builtin_amdgcn_mfma_f32_16x16x32_bf16(a1, bu.v, aoff1, 0, 0, 0);
      }
    }
    ow0 = aoff0[0] + ob[(kgrp << 2) + 0];
    ow1 = aoff0[1] + ob[(kgrp << 2) + 1];
    ow2 = aoff0[2] + ob[(kgrp << 2) + 2];
    ow3 = aoff0[3] + ob[(kgrp << 2) + 3];
    owA = aoff1[0] + ob[16];
    owB = aoff1[1] + ob[17];
  }

  // distribute intra-wave: lane needs (dy,dx) for all 9 taps of its pixel
  float dyk[9], dxk[9];
#pragma unroll
  for (int k = 0; k < 8; ++k) {
    int src = ((k >> 1) << 4) | pl;
    dyk[k] = __shfl((k & 1) ? ow2 : ow0, src, 64);
    dxk[k] = __shfl((k & 1) ? ow3 : ow1, src, 64);
  }
  dyk[8] = __shfl(owA, pl, 64);
  dxk[8] = __shfl(owB, pl, 64);

  // ---- phase 2: tap loop, branch-free, K-half only ----
  f32x4 acc[4];
#pragma unroll
  for (int mt = 0; mt < 4; ++mt) acc[mt] = (f32x4){0.f, 0.f, 0.f, 0.f};
  unsigned oobbits = 0;

#pragma unroll
  for (int k = 0; k < 9; ++k) {
    const float py = (float)(pyy + (k / 3) - 1) + dyk[k];
    const float px = (float)(pxx + (k % 3) - 1) + dxk[k];
    const float fy = floorf(py), fx = floorf(px);
    const int iy = (int)fy, ix = (int)fx;
    const float wy = py - fy, wx = px - fx;
    const float wy1 = 1.f - wy, wx1 = 1.f - wx;
    const bool ry0 = (unsigned)iy < (unsigned)H_;
    const bool ry1 = (unsigned)(iy + 1) < (unsigned)H_;
    const bool rx0 = (unsigned)ix < (unsigned)W_;
    const bool rx1 = (unsigned)(ix + 1) < (unsigned)W_;
    const float w00 = (ry0 & rx0) ? wy1 * wx1 : 0.f;
    const float w01 = (ry0 & rx1) ? wy1 * wx : 0.f;
    const float w10 = (ry1 & rx0) ? wy * wx1 : 0.f;
    const float w11 = (ry1 & rx1) ? wy * wx : 0.f;

    const int ly = iy - oy, lx = ix - ox;
    const int lyc = min(max(ly, 0), 13);
    const int lxc = min(max(lx, 0), 14);
    oobbits |= ((ly != lyc) | (lx != lxc)) ? (1u << k) : 0u;
    const int pt00 = (lyc << 4) | lxc;
    const int pt01 = pt00 + 1, pt10 = pt00 + 16, pt11 = pt00 + 17;

    u32x4 q00 = *(const u32x4*)&ldsx[(pt00 << 6) | ((mc8 ^ (pt00 & 7)) << 3)];
    u32x4 q01 = *(const u32x4*)&ldsx[(pt01 << 6) | ((mc8 ^ (pt01 & 7)) << 3)];
    u32x4 q10 = *(const u32x4*)&ldsx[(pt10 << 6) | ((mc8 ^ (pt10 & 7)) << 3)];
    u32x4 q11 = *(const u32x4*)&ldsx[(pt11 << 6) | ((mc8 ^ (pt11 & 7)) << 3)];

    union { bf16x8 v; u32x4 w; } bfr;
#pragma unroll
    for (int j = 0; j < 4; ++j) {
      float e = __uint_as_float(q00[j] << 16) * w00;
      e = fmaf(__uint_as_float(q01[j] << 16), w01, e);
      e = fmaf(__uint_as_float(q10[j] << 16), w10, e);
      e = fmaf(__uint_as_float(q11[j] << 16), w11, e);
      float o = __uint_as_float(q00[j] & 0xffff0000u) * w00;
      o = fmaf(__uint_as_float(q01[j] & 0xffff0000u), w01, o);
      o = fmaf(__uint_as_float(q10[j] & 0xffff0000u), w10, o);
      o = fmaf(__uint_as_float(q11[j] & 0xffff0000u), w11, o);
      bfr.w[j] = cvt_pk_bf16(e, o);
    }
#pragma unroll
    for (int mt = 0; mt < 4; ++mt) {
      bf16x8 af = *(const bf16x8*)&dwt[(k << 12) + (((mt << 4) | pl) << 6)
                                       + (wvh << 5) + (kgrp << 3)];
      acc[mt] = __builtin_amdgcn_mfma_f32_16x16x32_bf16(af, bfr.v, acc[mt], 0, 0, 0);
    }
  }

  // ---- cold repair: only if a sample strayed outside the halo tile ----
  if (__builtin_expect(__ballot(oobbits != 0u) != 0ull, 0)) {
#pragma unroll 1
    for (int k = 0; k < 9; ++k) {
      if (__ballot((oobbits >> k) & 1u) != 0ull) {
        const bool mine = ((oobbits >> k) & 1u) != 0u;
        const float py = (float)(pyy + (k / 3) - 1) + dyk[k];
        const float px = (float)(pxx + (k % 3) - 1) + dxk[k];
        const float fy = floorf(py), fx = floorf(px);
        const int iy = (int)fy, ix = (int)fx;
        const float wy = py - fy, wx = px - fx;
        const float wy1 = 1.f - wy, wx1 = 1.f - wx;
        const bool ry0 = (unsigned)iy < (unsigned)H_;
        const bool ry1 = (unsigned)(iy + 1) < (unsigned)H_;
        const bool rx0 = (unsigned)ix < (unsigned)W_;
        const bool rx1 = (unsigned)(ix + 1) < (unsigned)W_;
        const float w00 = (ry0 & rx0) ? wy1 * wx1 : 0.f;
        const float w01 = (ry0 & rx1) ? wy1 * wx : 0.f;
        const float w10 = (ry1 & rx0) ? wy * wx1 : 0.f;
        const float w11 = (ry1 & rx1) ? wy * wx : 0.f;
        const int ly = iy - oy, lx = ix - ox;
        const int lyc = min(max(ly, 0), 13);
        const int lxc = min(max(lx, 0), 14);
        const int pt00 = (lyc << 4) | lxc;
        const int y0 = min(max(iy, 0), H_ - 1), x0c = min(max(ix, 0), W_ - 1);
        const int y1 = min(max(iy + 1, 0), H_ - 1), x1c = min(max(ix + 1, 0), W_ - 1);
        u32x4 qq[4];
#pragma unroll
        for (int cr = 0; cr < 4; ++cr) {
          const int ptc = pt00 + ((cr >> 1) << 4) + (cr & 1);
          qq[cr] = *(const u32x4*)&ldsx[(ptc << 6) | ((mc8 ^ (ptc & 7)) << 3)];
        }
        const float* xb = x + (size_t)(b * CIN_ + (mc8 << 3)) * (H_ * W_);
        union { bf16x8 v; u32x4 w; } dfr;
#pragma unroll
        for (int j = 0; j < 4; ++j) {
          float d[2];
#pragma unroll
          for (int e2 = 0; e2 < 2; ++e2) {
            float s = __uint_as_float(e2 ? (qq[0][j] & 0xffff0000u) : (qq[0][j] << 16)) * w00;
            s = fmaf(__uint_as_float(e2 ? (qq[1][j] & 0xffff0000u) : (qq[1][j] << 16)), w01, s);
            s = fmaf(__uint_as_float(e2 ? (qq[2][j] & 0xffff0000u) : (qq[2][j] << 16)), w10, s);
            s = fmaf(__uint_as_float(e2 ? (qq[3][j] & 0xffff0000u) : (qq[3][j] << 16)), w11, s);
            const float* xc = xb + (size_t)(2 * j + e2) * (H_ * W_);
            float right = xc[y0 * W_ + x0c] * w00 + xc[y0 * W_ + x1c] * w01 +
                          xc[y1 * W_ + x0c] * w10 + xc[y1 * W_ + x1c] * w11;
            d[e2] = mine ? (right - s) : 0.f;
          }
          dfr.w[j] = cvt_pk_bf16(d[0], d[1]);
        }
#pragma unroll
        for (int mt = 0; mt < 4; ++mt) {
          bf16x8 a = *(const bf16x8*)&dwt[(k << 12) + (((mt << 4) | pl) << 6)
                                          + (wvh << 5) + (kgrp << 3)];
          acc[mt] = __builtin_amdgcn_mfma_f32_16x16x32_bf16(a, dfr.v, acc[mt], 0, 0, 0);
        }
      }
    }
  }

  // ---- epilogue: pair-sum partial accs via LDS, then store (wv<4) ----
  __syncthreads();                       // all ldsx reads done; safe to reuse
  float* lred = (float*)ldsx;            // 4 waves x 64 lanes x 16 f32 = 16 KB
  const int xsw = (lane >> 1) & 3;       // bank-spread XOR for 16B chunks
  if (wv >= 4) {
    const int base = (((wv - 4) << 6) | lane) << 4;
#pragma unroll
    for (int mt = 0; mt < 4; ++mt)
      *(f32x4*)&lred[base + ((mt ^ xsw) << 2)] = acc[mt];
  }
  __syncthreads();
  if (wv < 4) {
    const int base = ((wv << 6) | lane) << 4;
#pragma unroll
    for (int mt = 0; mt < 4; ++mt) {
      f32x4 p = *(const f32x4*)&lred[base + ((mt ^ xsw) << 2)];
#pragma unroll
      for (int j = 0; j < 4; ++j) {
        int o = (mt << 4) | (kgrp << 2) | j;
        float v = acc[mt][j] + p[j] + db[o];
        out[((b * COUT_ + o) * H_ + pyy) * W_ + pxx] = v > 0.f ? v : 0.f;
      }
    }
  }
}

extern "C" void kernel_launch(void* const* d_in, const int* in_sizes, int n_in,
                              void* d_out, int out_size, void* d_ws, size_t ws_size,
                              hipStream_t stream) {
  const float* x  = (const float*)d_in[0];
  const float* ow = (const float*)d_in[1];
  const float* ob = (const float*)d_in[2];
  const float* dw = (const float*)d_in[3];
  const float* db = (const float*)d_in[4];
  float* out = (float*)d_out;

  unsigned short* dwt = (unsigned short*)d_ws;                    // 36864 bf16
  unsigned short* owt = (unsigned short*)((char*)d_ws + 73728);   // 18432 bf16

  hipLaunchKernelGGL(prep_w, dim3(216), dim3(256), 0, stream, dw, ow, dwt, owt);
  hipLaunchKernelGGL(deform_main, dim3(2048), dim3(512), 0, stream,
                     x, owt, ob, dwt, db, out);
}

// Round 7
// 193.314 us; speedup vs baseline: 1.3510x; 1.3510x over previous
//
#include <hip/hip_runtime.h>
#include <hip/hip_bf16.h>

#define H_ 128
#define W_ 128
#define B_ 8
#define CIN_ 64
#define COUT_ 64

typedef __attribute__((ext_vector_type(8))) short bf16x8;
typedef __attribute__((ext_vector_type(4))) float f32x4;
typedef __attribute__((ext_vector_type(4))) unsigned int u32x4;

static __device__ __forceinline__ unsigned short f2bf(float f) {
  union { float f; unsigned int u; } a; a.f = f;
  unsigned int u = a.u;
  return (unsigned short)((u + 0x7fffu + ((u >> 16) & 1u)) >> 16);  // RNE, finite
}

static __device__ __forceinline__ unsigned int cvt_pk_bf16(float lo, float hi) {
  unsigned int r;
  asm("v_cvt_pk_bf16_f32 %0, %1, %2" : "=v"(r) : "v"(lo), "v"(hi));
  return r;
}

// ---------------- prep: transpose both weight tensors to bf16 ----------------
// dwt: (o,c,k) f32 -> [k][o(64)][c(64)] bf16      (36864 elems)
// owt: (18,c,t) f32 -> [t][om(32, zero-pad)][c(64)] bf16  (18432 elems)
__global__ __launch_bounds__(256) void prep_w(const float* __restrict__ dw,
    const float* __restrict__ ow, unsigned short* __restrict__ dwt,
    unsigned short* __restrict__ owt) {
  int id = blockIdx.x * 256 + threadIdx.x;
  if (id < 36864) {
    int c = id & 63, o = (id >> 6) & 63, k = id >> 12;
    dwt[id] = f2bf(dw[(o * 64 + c) * 9 + k]);
  } else if (id < 36864 + 18432) {
    int j = id - 36864;
    int c = j & 63, om = (j >> 6) & 31, t = j >> 11;
    owt[j] = f2bf(om < 18 ? ow[(om * 64 + c) * 9 + t] : 0.f);
  }
}

// ---------------- fused deformable block ----------------
// grid = B*16*16 (8x8 pixel tiles), block 256 = 4 waves.
// Wave wv owns pixels [wv*16, wv*16+16), computes all 64 couts (4 M-tiles).
// x-tile in LDS: rows [ty-3,ty+11] (15) x cols [tx-4,tx+11] (16), [pt][c] bf16,
// 16B-slot XOR swizzle (c8 ^ (pt&7)).
// I-CACHE DISCIPLINE (R7): tap loop and phase-1 are ROLLED (#pragma unroll 1) --
// fully-unrolled versions (~50KB code) were I-fetch-bound at ~24% VALUBusy.
// Per-tap offsets live in a tiny LDS table (intra-wave write/read, no barrier)
// because register arrays indexed by runtime k would spill (rule #20).

__global__ __launch_bounds__(256, 4) void deform_main(const float* __restrict__ x,
    const unsigned short* __restrict__ owt, const float* __restrict__ ob,
    const unsigned short* __restrict__ dwt, const float* __restrict__ db,
    float* __restrict__ out) {
  __shared__ __attribute__((aligned(16))) unsigned short ldsx[240 * 64]; // 30 KB
  __shared__ float dyx[9][64][2];                                        // 4.5 KB

  const int tid = threadIdx.x;
  // XCD swizzle: XCD x gets contiguous range = batch image b=x (L2 locality).
  const int blk = ((blockIdx.x & 7) << 8) | (blockIdx.x >> 3);
  const int b = blk >> 8;
  const int ty = ((blk >> 4) & 15) << 3;
  const int tx = (blk & 15) << 3;
  const int oy = ty - 3, ox = tx - 4;
  const int lane = tid & 63;
  const int wv = tid >> 6;
  const int pl = lane & 15;
  const int kgrp = lane >> 4;                // 0..3 (K-slice group)
  const int pwl = (wv << 4) | pl;            // this lane's pixel 0..63
  const int pyy = ty + (pwl >> 3), pxx = tx + (pwl & 7);

  // ---- phase 0: stage x tile, one (pt, all c) per thread; rolled x2 ----
  {
    int pt = tid;                    // 0..255, valid < 240
    if (pt < 240) {
      int gy = oy + (pt >> 4), gx = ox + (pt & 15);
      bool ok = ((unsigned)gy < (unsigned)H_) && ((unsigned)gx < (unsigned)W_);
      int base = ((b * CIN_) * H_ + gy) * W_ + gx;
#pragma unroll 2
      for (int c8 = 0; c8 < 8; ++c8) {
        float v[8];
#pragma unroll
        for (int ci = 0; ci < 8; ++ci)
          v[ci] = ok ? x[base + ((c8 << 3) + ci) * (H_ * W_)] : 0.f;
        u32x4 sv;
#pragma unroll
        for (int j = 0; j < 4; ++j) sv[j] = cvt_pk_bf16(v[2 * j], v[2 * j + 1]);
        *(u32x4*)&ldsx[(pt << 6) | ((c8 ^ (pt & 7)) << 3)] = sv;
      }
    }
  }
  __syncthreads();

  // ---- phase 1: offset conv via MFMA, ROLLED over taps ----
  {
    f32x4 aoff0 = (f32x4){0.f, 0.f, 0.f, 0.f};
    f32x4 aoff1 = (f32x4){0.f, 0.f, 0.f, 0.f};
#pragma unroll 1
    for (int t = 0; t < 9; ++t) {
      const int ly1 = (pwl >> 3) + (t / 3) + 2;   // (t/3 - 1) + 3
      const int lx1 = (pwl & 7) + (t % 3) + 3;    // (t%3 - 1) + 4
      const int ptt = (ly1 << 4) | lx1;
#pragma unroll
      for (int hf = 0; hf < 2; ++hf) {
        const int c8 = (hf << 2) | kgrp;
        bf16x8 a0 = *(const bf16x8*)&owt[(((t << 5) | pl) << 6) | (c8 << 3)];
        bf16x8 a1 = *(const bf16x8*)&owt[(((t << 5) | 16 | pl) << 6) | (c8 << 3)];
        union { u32x4 w; bf16x8 v; } bu;
        bu.w = *(const u32x4*)&ldsx[(ptt << 6) | ((c8 ^ (ptt & 7)) << 3)];
        aoff0 = __builtin_amdgcn_mfma_f32_16x16x32_bf16(a0, bu.v, aoff0, 0, 0, 0);
        aoff1 = __builtin_amdgcn_mfma_f32_16x16x32_bf16(a1, bu.v, aoff1, 0, 0, 0);
      }
    }
    // lane (kgrp,pl) owns offsets o=4*kgrp+j for pixel pwl:
    //   o=2k -> dy of tap k; o=2k+1 -> dx.  Write taps 2*kgrp, 2*kgrp+1 (+ tap 8).
    float2 t0 = make_float2(aoff0[0] + ob[(kgrp << 2) + 0],
                            aoff0[1] + ob[(kgrp << 2) + 1]);
    float2 t1 = make_float2(aoff0[2] + ob[(kgrp << 2) + 2],
                            aoff0[3] + ob[(kgrp << 2) + 3]);
    *(float2*)&dyx[2 * kgrp][pwl][0] = t0;
    *(float2*)&dyx[2 * kgrp + 1][pwl][0] = t1;
    if (kgrp == 0) {
      float2 t8 = make_float2(aoff1[0] + ob[16], aoff1[1] + ob[17]);
      *(float2*)&dyx[8][pwl][0] = t8;
    }
  }
  // no barrier: each wave writes/reads only its own pixels' table entries

  // ---- phase 2: tap loop, ROLLED, branch-free ----
  f32x4 acc[4];
#pragma unroll
  for (int mt = 0; mt < 4; ++mt) acc[mt] = (f32x4){0.f, 0.f, 0.f, 0.f};
  unsigned oobbits = 0;

#pragma unroll 1
  for (int k = 0; k < 9; ++k) {
    // A-fragments first: L2 latency overlaps the ds_read + bilinear chain
    bf16x8 af0[4], af1[4];
#pragma unroll
    for (int mt = 0; mt < 4; ++mt) {
      af0[mt] = *(const bf16x8*)&dwt[(k << 12) + (((mt << 4) | pl) << 6) + (kgrp << 3)];
      af1[mt] = *(const bf16x8*)&dwt[(k << 12) + (((mt << 4) | pl) << 6) + 32 + (kgrp << 3)];
    }

    const float2 dd = *(const float2*)&dyx[k][pwl][0];
    const float py = (float)(pyy + (k / 3) - 1) + dd.x;
    const float px = (float)(pxx + (k % 3) - 1) + dd.y;
    const float fy = floorf(py), fx = floorf(px);
    const int iy = (int)fy, ix = (int)fx;
    const float wy = py - fy, wx = px - fx;
    const float wy1 = 1.f - wy, wx1 = 1.f - wx;
    const bool ry0 = (unsigned)iy < (unsigned)H_;
    const bool ry1 = (unsigned)(iy + 1) < (unsigned)H_;
    const bool rx0 = (unsigned)ix < (unsigned)W_;
    const bool rx1 = (unsigned)(ix + 1) < (unsigned)W_;
    const float w00 = (ry0 & rx0) ? wy1 * wx1 : 0.f;
    const float w01 = (ry0 & rx1) ? wy1 * wx : 0.f;
    const float w10 = (ry1 & rx0) ? wy * wx1 : 0.f;
    const float w11 = (ry1 & rx1) ? wy * wx : 0.f;

    const int ly = iy - oy, lx = ix - ox;
    const int lyc = min(max(ly, 0), 13);
    const int lxc = min(max(lx, 0), 14);
    oobbits |= ((ly != lyc) | (lx != lxc)) ? (1u << k) : 0u;
    const int pt00 = (lyc << 4) | lxc;

    union { bf16x8 v; u32x4 w; } bfr0, bfr1;
#pragma unroll
    for (int hf = 0; hf < 2; ++hf) {
      const int c8 = (hf << 2) | kgrp;
      const int p01 = pt00 + 1, p10 = pt00 + 16, p11 = pt00 + 17;
      u32x4 q00 = *(const u32x4*)&ldsx[(pt00 << 6) | ((c8 ^ (pt00 & 7)) << 3)];
      u32x4 q01 = *(const u32x4*)&ldsx[(p01 << 6) | ((c8 ^ (p01 & 7)) << 3)];
      u32x4 q10 = *(const u32x4*)&ldsx[(p10 << 6) | ((c8 ^ (p10 & 7)) << 3)];
      u32x4 q11 = *(const u32x4*)&ldsx[(p11 << 6) | ((c8 ^ (p11 & 7)) << 3)];
#pragma unroll
      for (int j = 0; j < 4; ++j) {
        float e = __uint_as_float(q00[j] << 16) * w00;
        e = fmaf(__uint_as_float(q01[j] << 16), w01, e);
        e = fmaf(__uint_as_float(q10[j] << 16), w10, e);
        e = fmaf(__uint_as_float(q11[j] << 16), w11, e);
        float o = __uint_as_float(q00[j] & 0xffff0000u) * w00;
        o = fmaf(__uint_as_float(q01[j] & 0xffff0000u), w01, o);
        o = fmaf(__uint_as_float(q10[j] & 0xffff0000u), w10, o);
        o = fmaf(__uint_as_float(q11[j] & 0xffff0000u), w11, o);
        if (hf == 0) bfr0.w[j] = cvt_pk_bf16(e, o);
        else         bfr1.w[j] = cvt_pk_bf16(e, o);
      }
    }
#pragma unroll
    for (int mt = 0; mt < 4; ++mt)
      acc[mt] = __builtin_amdgcn_mfma_f32_16x16x32_bf16(af0[mt], bfr0.v, acc[mt], 0, 0, 0);
#pragma unroll
    for (int mt = 0; mt < 4; ++mt)
      acc[mt] = __builtin_amdgcn_mfma_f32_16x16x32_bf16(af1[mt], bfr1.v, acc[mt], 0, 0, 0);
  }

  // ---- cold repair: only if a sample strayed outside the halo tile ----
  if (__builtin_expect(__ballot(oobbits != 0u) != 0ull, 0)) {
#pragma unroll 1
    for (int k = 0; k < 9; ++k) {
      if (__ballot((oobbits >> k) & 1u) != 0ull) {
        const bool mine = ((oobbits >> k) & 1u) != 0u;
        const float2 dd = *(const float2*)&dyx[k][pwl][0];
        const float py = (float)(pyy + (k / 3) - 1) + dd.x;
        const float px = (float)(pxx + (k % 3) - 1) + dd.y;
        const float fy = floorf(py), fx = floorf(px);
        const int iy = (int)fy, ix = (int)fx;
        const float wy = py - fy, wx = px - fx;
        const float wy1 = 1.f - wy, wx1 = 1.f - wx;
        const bool ry0 = (unsigned)iy < (unsigned)H_;
        const bool ry1 = (unsigned)(iy + 1) < (unsigned)H_;
        const bool rx0 = (unsigned)ix < (unsigned)W_;
        const bool rx1 = (unsigned)(ix + 1) < (unsigned)W_;
        const float w00 = (ry0 & rx0) ? wy1 * wx1 : 0.f;
        const float w01 = (ry0 & rx1) ? wy1 * wx : 0.f;
        const float w10 = (ry1 & rx0) ? wy * wx1 : 0.f;
        const float w11 = (ry1 & rx1) ? wy * wx : 0.f;
        const int ly = iy - oy, lx = ix - ox;
        const int lyc = min(max(ly, 0), 13);
        const int lxc = min(max(lx, 0), 14);
        const int pt00 = (lyc << 4) | lxc;
        const int y0 = min(max(iy, 0), H_ - 1), x0c = min(max(ix, 0), W_ - 1);
        const int y1 = min(max(iy + 1, 0), H_ - 1), x1c = min(max(ix + 1, 0), W_ - 1);
#pragma unroll 1
        for (int hf = 0; hf < 2; ++hf) {
          const int c8 = (hf << 2) | kgrp;
          u32x4 qq[4];
#pragma unroll
          for (int cr = 0; cr < 4; ++cr) {
            const int ptc = pt00 + ((cr >> 1) << 4) + (cr & 1);
            qq[cr] = *(const u32x4*)&ldsx[(ptc << 6) | ((c8 ^ (ptc & 7)) << 3)];
          }
          const float* xb = x + (size_t)(b * CIN_ + (c8 << 3)) * (H_ * W_);
          union { bf16x8 v; u32x4 w; } dfr;
#pragma unroll
          for (int j = 0; j < 4; ++j) {
            float d[2];
#pragma unroll
            for (int e2 = 0; e2 < 2; ++e2) {
              float s = __uint_as_float(e2 ? (qq[0][j] & 0xffff0000u) : (qq[0][j] << 16)) * w00;
              s = fmaf(__uint_as_float(e2 ? (qq[1][j] & 0xffff0000u) : (qq[1][j] << 16)), w01, s);
              s = fmaf(__uint_as_float(e2 ? (qq[2][j] & 0xffff0000u) : (qq[2][j] << 16)), w10, s);
              s = fmaf(__uint_as_float(e2 ? (qq[3][j] & 0xffff0000u) : (qq[3][j] << 16)), w11, s);
              const float* xc = xb + (size_t)(2 * j + e2) * (H_ * W_);
              float right = xc[y0 * W_ + x0c] * w00 + xc[y0 * W_ + x1c] * w01 +
                            xc[y1 * W_ + x0c] * w10 + xc[y1 * W_ + x1c] * w11;
              d[e2] = mine ? (right - s) : 0.f;
            }
            dfr.w[j] = cvt_pk_bf16(d[0], d[1]);
          }
#pragma unroll
          for (int mt = 0; mt < 4; ++mt) {
            bf16x8 a = *(const bf16x8*)&dwt[(k << 12) + (((mt << 4) | pl) << 6)
                                            + (hf << 5) + (kgrp << 3)];
            acc[mt] = __builtin_amdgcn_mfma_f32_16x16x32_bf16(a, dfr.v, acc[mt], 0, 0, 0);
          }
        }
      }
    }
  }

  // ---- epilogue: D col=lane&15 (pixel), row=(lane>>4)*4+j (cout in M-tile) ----
#pragma unroll
  for (int mt = 0; mt < 4; ++mt) {
#pragma unroll
    for (int j = 0; j < 4; ++j) {
      int o = (mt << 4) | (kgrp << 2) | j;
      float v = acc[mt][j] + db[o];
      out[((b * COUT_ + o) * H_ + pyy) * W_ + pxx] = v > 0.f ? v : 0.f;
    }
  }
}

extern "C" void kernel_launch(void* const* d_in, const int* in_sizes, int n_in,
                              void* d_out, int out_size, void* d_ws, size_t ws_size,
                              hipStream_t stream) {
  const float* x  = (const float*)d_in[0];
  const float* ow = (const float*)d_in[1];
  const float* ob = (const float*)d_in[2];
  const float* dw = (const float*)d_in[3];
  const float* db = (const float*)d_in[4];
  float* out = (float*)d_out;

  unsigned short* dwt = (unsigned short*)d_ws;                    // 36864 bf16
  unsigned short* owt = (unsigned short*)((char*)d_ws + 73728);   // 18432 bf16

  hipLaunchKernelGGL(prep_w, dim3(216), dim3(256), 0, stream, dw, ow, dwt, owt);
  hipLaunchKernelGGL(deform_main, dim3(2048), dim3(256), 0, stream,
                     x, owt, ob, dwt, db, out);
}